// Round 4
// baseline (1290.651 us; speedup 1.0000x reference)
//
#include <hip/hip_runtime.h>
#include <cstdint>
#include <cstddef>

#define NTOK 8192
#define C_ 1024
#define H_ 4096
#define E_ 8
#define YMAX1 40  // max 256-row tiles over 8 experts: 8192/256 + 8 pad
#define YMAX2 72  // max 128-row tiles over 8 experts: 8192/128 + 8 pad

typedef __attribute__((ext_vector_type(8))) short short8;
typedef __attribute__((ext_vector_type(4))) float f32x4;
typedef __attribute__((ext_vector_type(4))) unsigned int u32x4;

__device__ __forceinline__ uint16_t f2b(float f) {
    uint32_t x;
    __builtin_memcpy(&x, &f, 4);
    x = (x + 0x7fffu + ((x >> 16) & 1u)) >> 16;  // round-to-nearest-even
    return (uint16_t)x;
}

// tanh-form GELU, NaN-safe; |err vs erf-gelu| < ~3e-3 (threshold headroom 0.04)
__device__ __forceinline__ float gelu_f(float v) {
    float u = v * (0.7978845608028654f + 0.03567740814183f * v * v);
    float t = __expf(2.f * u);
    float th = 1.f - 2.f / (t + 1.f);
    return 0.5f * v * (1.f + th);
}

// ---------------- router: one wave per token, fp32 logits -> first-argmax ---
__global__ __launch_bounds__(256) void router_kernel(
    const float* __restrict__ x, const float* __restrict__ wr,
    const float* __restrict__ br, int* __restrict__ top1)
{
    int wid = threadIdx.x >> 6, lane = threadIdx.x & 63;
    int tok = blockIdx.x * 4 + wid;
    const float* xrow = x + (size_t)tok * C_;
    float acc[E_];
#pragma unroll
    for (int e = 0; e < E_; e++) acc[e] = 0.f;
#pragma unroll 4
    for (int i = 0; i < C_ / 64; i++) {
        int c = i * 64 + lane;
        float xv = xrow[c];
        const f32x4 w0 = *(const f32x4*)(wr + (size_t)c * E_);
        const f32x4 w1v = *(const f32x4*)(wr + (size_t)c * E_ + 4);
#pragma unroll
        for (int e = 0; e < 4; e++) acc[e] += xv * w0[e];
#pragma unroll
        for (int e = 0; e < 4; e++) acc[4 + e] += xv * w1v[e];
    }
#pragma unroll
    for (int off = 32; off > 0; off >>= 1) {
#pragma unroll
        for (int e = 0; e < E_; e++) acc[e] += __shfl_xor(acc[e], off, 64);
    }
    if (lane == 0) {
        float best = acc[0] + br[0];
        int bi = 0;
#pragma unroll
        for (int e = 1; e < E_; e++) {
            float v = acc[e] + br[e];
            if (v > best) { best = v; bi = e; }  // strict > == first-max (np argmax)
        }
        top1[tok] = bi;
    }
}

__global__ void zero_counts(int* counts) {
    if (threadIdx.x < E_) counts[threadIdx.x] = 0;
}

// two-level scatter: LDS histogram per block, 8 global atomics per block
// (order within an expert is irrelevant: outputs are written per-token).
__global__ __launch_bounds__(1024) void scatter_kernel(
    const int* __restrict__ top1, int* counts, int* __restrict__ idx)
{
    __shared__ int lc[E_], base[E_];
    int tid = threadIdx.x;
    if (tid < E_) lc[tid] = 0;
    __syncthreads();
    int t = blockIdx.x * 1024 + tid;
    int e = top1[t];
    int my = atomicAdd(&lc[e], 1);
    __syncthreads();
    if (tid < E_) base[tid] = atomicAdd(&counts[tid], lc[tid]);
    __syncthreads();
    idx[e * NTOK + base[e] + my] = t;
}

// ---- plan: compact (expert, mb) tile tables for 256-row and 128-row tiles --
// ranges layout: [0..1]=all experts, [2..3]=experts 0..3, [4..5]=experts 4..7
__global__ void plan_kernel(const int* __restrict__ counts,
                            int* __restrict__ tab1, int* __restrict__ ranges1,
                            int* __restrict__ tab2, int* __restrict__ ranges2)
{
    if (threadIdx.x == 0) {
        int n = 0, n0 = 0;
        for (int e = 0; e < E_; e++) {
            int nt = (counts[e] + 255) >> 8;
            for (int mb = 0; mb < nt; mb++) tab1[n++] = (e << 16) | mb;
            if (e == 3) n0 = n;
        }
        ranges1[0] = 0;  ranges1[1] = n;
        ranges1[2] = 0;  ranges1[3] = n0;
        ranges1[4] = n0; ranges1[5] = n;

        n = 0; n0 = 0;
        for (int e = 0; e < E_; e++) {
            int nt = (counts[e] + 127) >> 7;
            for (int mb = 0; mb < nt; mb++) tab2[n++] = (e << 16) | mb;
            if (e == 3) n0 = n;
        }
        ranges2[0] = 0;  ranges2[1] = n;
        ranges2[2] = 0;  ranges2[3] = n0;
        ranges2[4] = n0; ranges2[5] = n;
    }
}

// ---------------- x fp32 -> bf16 --------------------------------------------
__global__ __launch_bounds__(256) void convert_x_kernel(
    const float* __restrict__ x, uint16_t* __restrict__ xb)
{
    size_t i = ((size_t)blockIdx.x * 256 + threadIdx.x) * 8;
    f32x4 a = *(const f32x4*)(x + i);
    f32x4 b = *(const f32x4*)(x + i + 4);
    u32x4 o;
    o.x = (uint32_t)f2b(a.x) | ((uint32_t)f2b(a.y) << 16);
    o.y = (uint32_t)f2b(a.z) | ((uint32_t)f2b(a.w) << 16);
    o.z = (uint32_t)f2b(b.x) | ((uint32_t)f2b(b.y) << 16);
    o.w = (uint32_t)f2b(b.z) | ((uint32_t)f2b(b.w) << 16);
    *(u32x4*)(xb + i) = o;
}

// ------- transpose+convert: w fp32 [E][K][N] -> wt bf16 [ez][N][K] ----------
__global__ __launch_bounds__(256) void transpose_cvt_kernel(
    const float* __restrict__ w, uint16_t* __restrict__ wt,
    int K, int N, int ebase)
{
    __shared__ uint16_t tile[64][66];
    int ez = blockIdx.z, e = ebase + ez;
    int n0 = blockIdx.x * 64, k0 = blockIdx.y * 64;
    int t = threadIdx.x;
#pragma unroll
    for (int i = 0; i < 4; i++) {
        int chunk = i * 256 + t;
        int r = chunk >> 4, c4 = chunk & 15;
        f32x4 v = *(const f32x4*)(w + (size_t)(e * K + k0 + r) * N + n0 + c4 * 4);
        uint32_t u0 = (uint32_t)f2b(v.x) | ((uint32_t)f2b(v.y) << 16);
        uint32_t u1 = (uint32_t)f2b(v.z) | ((uint32_t)f2b(v.w) << 16);
        *(uint32_t*)&tile[r][c4 * 4 + 0] = u0;
        *(uint32_t*)&tile[r][c4 * 4 + 2] = u1;
    }
    __syncthreads();
#pragma unroll
    for (int i = 0; i < 2; i++) {
        int chunk = i * 256 + t;
        int rn = chunk >> 3, ck = chunk & 7;
        uint32_t p[4];
#pragma unroll
        for (int j = 0; j < 4; j++) {
            uint32_t lo = tile[ck * 8 + 2 * j][rn];
            uint32_t hi = tile[ck * 8 + 2 * j + 1][rn];
            p[j] = lo | (hi << 16);
        }
        u32x4 v; v.x = p[0]; v.y = p[1]; v.z = p[2]; v.w = p[3];
        *(u32x4*)(wt + ((size_t)ez * N + n0 + rn) * K + k0 + ck * 8) = v;
    }
}

// ---------------- grouped GEMM: reg-staged, single-buffer, 2-phase ----------
// A bf16 [NTOK][K] gathered by token id; Bt bf16 [ez][N][K] k-contig.
// BM x BN tile, NW threads = NW/64 waves (WM x WN), per-wave (BM/WM)x(BN/WN).
// Staging: global_load_dwordx4 -> VGPR issued for kt+1 BEFORE compute(kt)
// (precise reg waitcnt, deep VMEM queue) -> ds_write_b128 after the post-
// compute barrier (T14 issue-early/write-late; proven R3: 210->142 us).
// LDS rows BK elems = CPR chunks of 8; chunk j of row r holds global chunk
// j ^ swz(r), swz = r&7 (BK=64, G4 recipe) or (r>>1)&3 (BK=32, R3-verified).
// Both sides of the involution applied -> fragment ds_read_b128 2-way max.
// T1: bijective XCD-chunked block swizzle (grid % 8 == 0 by construction).
template <int BM, int BN, int BK, int NW, int WM, int WN, int MINW,
          int YB, int K, int N, typename OutT, bool GELU>
__global__ __launch_bounds__(NW, MINW) void gemm_kernel(
    const uint16_t* __restrict__ A, const uint16_t* __restrict__ Bt,
    const float* __restrict__ bias, OutT* __restrict__ Out,
    const int* __restrict__ counts, const int* __restrict__ idx,
    const int* __restrict__ tab, const int* __restrict__ range, int ebase)
{
    constexpr int MR = BM / (WM * 16);      // m-frags per wave
    constexpr int NT = BN / (WN * 16);      // n-frags per wave
    constexpr int CPR = BK / 8;             // 8-elem chunks per LDS row
    constexpr int AI = BM * BK / (8 * NW);  // A 16B-loads per thread per step
    constexpr int BI = BN * BK / (8 * NW);  // B 16B-loads per thread per step
    constexpr int KS = BK / 32;             // 32-k MFMA slices per step
    constexpr int NITER = K / BK;
    constexpr int GX = N / BN;
    constexpr int NWG = GX * YB;
    static_assert(NWG % 8 == 0, "grid must be divisible by 8 XCDs");
    static_assert(CPR == 4 || CPR == 8, "BK must be 32 or 64");

    // T1: XCD-chunked bijective swizzle of the flattened grid
    int o = blockIdx.y * GX + blockIdx.x;
    int lid = (o & 7) * (NWG / 8) + (o >> 3);
    int nb = lid % GX;
    int tile = range[0] + lid / GX;
    if (tile >= range[1]) return;
    int ent = tab[tile];
    int e = ent >> 16, mb = ent & 0xffff;
    int ez = e - ebase;
    int cnt = counts[e];

    __shared__ __align__(16) uint16_t As[BM][BK];
    __shared__ __align__(16) uint16_t Bs[BN][BK];

    int t = threadIdx.x;
    int lane = t & 63, w = t >> 6;
    int wm = w / WN, wn = w % WN;

    const int* idxe = idx + e * NTOK;

    f32x4 acc[MR][NT];
#pragma unroll
    for (int mt = 0; mt < MR; mt++)
#pragma unroll
        for (int nt = 0; nt < NT; nt++) acc[mt][nt] = (f32x4)(0.f);

    const uint16_t* Bte = Bt + ((size_t)ez * N + (size_t)nb * BN) * K;
    uint16_t* As0 = &As[0][0];
    uint16_t* Bs0 = &Bs[0][0];

    // staging addresses: LDS chunk j (of CPR per row) <- global chunk
    // j ^ swz(r) of the current BK-k window.
    const uint16_t* aptr[AI];
    const uint16_t* bptr[BI];
#pragma unroll
    for (int i = 0; i < AI; i++) {
        int cid = i * NW + t;
        int r = cid / CPR, j = cid % CPR;
        int sw = (CPR == 8) ? (r & 7) : ((r >> 1) & 3);
        int s = mb * BM + r;
        int tk = idxe[(s < cnt) ? s : 0];
        aptr[i] = A + (size_t)tk * K + (j ^ sw) * 8;
    }
#pragma unroll
    for (int i = 0; i < BI; i++) {
        int cid = i * NW + t;
        int r = cid / CPR, j = cid % CPR;
        int sw = (CPR == 8) ? (r & 7) : ((r >> 1) & 3);
        bptr[i] = Bte + (size_t)r * K + (j ^ sw) * 8;
    }

    u32x4 ra[AI], rb[BI];
    auto loadreg = [&](int kt) {
        int k0 = kt * BK;
#pragma unroll
        for (int i = 0; i < AI; i++) ra[i] = *(const u32x4*)(aptr[i] + k0);
#pragma unroll
        for (int i = 0; i < BI; i++) rb[i] = *(const u32x4*)(bptr[i] + k0);
    };
    auto ldswrite = [&]() {
#pragma unroll
        for (int i = 0; i < AI; i++) *(u32x4*)(As0 + (size_t)(i * NW + t) * 8) = ra[i];
#pragma unroll
        for (int i = 0; i < BI; i++) *(u32x4*)(Bs0 + (size_t)(i * NW + t) * 8) = rb[i];
    };

    auto compute = [&]() {
#pragma unroll
        for (int ks = 0; ks < KS; ks++) {
            // fragment chunk: global chunk g = ks*4 + (lane>>4), stored at
            // g ^ swz(row); row = 16-aligned base + (lane&15).
            int cs;
            if constexpr (CPR == 8)
                cs = (((ks * 4 + (lane >> 4)) ^ (lane & 7)) & 7) * 8;
            else
                cs = (((lane >> 4) ^ ((lane & 15) >> 1)) & 3) * 8;
            short8 af[MR], bf[NT];
#pragma unroll
            for (int mt = 0; mt < MR; mt++)
                af[mt] = *(const short8*)
                    (As0 + (wm * (BM / WM) + mt * 16 + (lane & 15)) * BK + cs);
#pragma unroll
            for (int nt = 0; nt < NT; nt++)
                bf[nt] = *(const short8*)
                    (Bs0 + (wn * (BN / WN) + nt * 16 + (lane & 15)) * BK + cs);
#pragma unroll
            for (int mt = 0; mt < MR; mt++)
#pragma unroll
                for (int nt = 0; nt < NT; nt++)
                    acc[mt][nt] = __builtin_amdgcn_mfma_f32_16x16x32_bf16(
                        af[mt], bf[nt], acc[mt][nt], 0, 0, 0);
        }
    };

    // prologue: stage K-step 0
    loadreg(0);
    ldswrite();
    __syncthreads();

    // steady state: issue loads(kt+1) -> compute(kt) -> sync (prefetch
    // arrival wait lands here, covered by compute) -> ds_write -> sync.
    for (int kt = 0; kt < NITER - 1; ++kt) {
        loadreg(kt + 1);
        __builtin_amdgcn_sched_barrier(0);  // keep load issue above compute
        compute();
        __syncthreads();
        ldswrite();
        __syncthreads();
    }
    compute();

    // epilogue: C/D layout col=lane&15, row=(lane>>4)*4+reg  [m89-verified]
    const float* be = bias + (size_t)e * N;
#pragma unroll
    for (int mt = 0; mt < MR; mt++) {
        int rbase = wm * (BM / WM) + mt * 16 + (lane >> 4) * 4;
#pragma unroll
        for (int r = 0; r < 4; r++) {
            int row = rbase + r;
            int s = mb * BM + row;
            if (s < cnt) {
                int tk = idxe[s];
#pragma unroll
                for (int nt = 0; nt < NT; nt++) {
                    int gcol = nb * BN + wn * (BN / WN) + nt * 16 + (lane & 15);
                    float v = acc[mt][nt][r] + be[gcol];
                    if (GELU) v = gelu_f(v);
                    if constexpr (sizeof(OutT) == 2)
                        Out[(size_t)tk * N + gcol] = (OutT)f2b(v);
                    else
                        Out[(size_t)tk * N + gcol] = v;
                }
            }
        }
    }
}

extern "C" void kernel_launch(void* const* d_in, const int* in_sizes, int n_in,
                              void* d_out, int out_size, void* d_ws, size_t ws_size,
                              hipStream_t stream)
{
    const float* x  = (const float*)d_in[0];
    const float* wr = (const float*)d_in[1];
    const float* br = (const float*)d_in[2];
    const float* b1 = (const float*)d_in[4];
    const float* w1 = (const float*)d_in[3];
    const float* w2 = (const float*)d_in[5];
    const float* b2 = (const float*)d_in[6];
    float* out = (float*)d_out;

    char* ws = (char*)d_ws;
    int* counts    = (int*)ws;                          // 32 B
    int* top1      = (int*)(ws + 1024);                 // 32 KiB
    int* idx       = (int*)(ws + 64 * 1024);            // 256 KiB
    int* tab1      = (int*)(ws + 384 * 1024);           // 40 ints (256-row tiles)
    int* ranges1   = (int*)(ws + 388 * 1024);           // 6 ints
    int* tab2      = (int*)(ws + 392 * 1024);           // 72 ints (128-row tiles)
    int* ranges2   = (int*)(ws + 396 * 1024);           // 6 ints
    uint16_t* xb   = (uint16_t*)(ws + ((size_t)1 << 20));   // 16 MiB
    uint16_t* hbuf = (uint16_t*)(ws + ((size_t)17 << 20));  // 64 MiB
    uint16_t* wT   = (uint16_t*)(ws + ((size_t)81 << 20));  // 64 MiB (big) / 32 MiB

    // big path needs 81 + 64 = 145 MiB of ws; fallback (113 MiB) is proven.
    bool big = ws_size >= ((size_t)145 << 20);

    hipLaunchKernelGGL(zero_counts, dim3(1), dim3(64), 0, stream, counts);
    hipLaunchKernelGGL(router_kernel, dim3(NTOK / 4), dim3(256), 0, stream,
                       x, wr, br, top1);
    hipLaunchKernelGGL(scatter_kernel, dim3(NTOK / 1024), dim3(1024), 0, stream,
                       top1, counts, idx);
    hipLaunchKernelGGL(plan_kernel, dim3(1), dim3(64), 0, stream,
                       counts, tab1, ranges1, tab2, ranges2);
    hipLaunchKernelGGL(convert_x_kernel, dim3(NTOK * C_ / (256 * 8)), dim3(256), 0,
                       stream, x, xb);

    if (big) {
        // GEMM1: h = gelu(x @ w1 + b1), 256x256 BK=64, 512 thr, MR=8 per wave
        hipLaunchKernelGGL(transpose_cvt_kernel, dim3(H_ / 64, C_ / 64, E_),
                           dim3(256), 0, stream, w1, wT, C_, H_, 0);
        hipLaunchKernelGGL((gemm_kernel<256, 256, 64, 512, 2, 4, 2,
                                        YMAX1, C_, H_, uint16_t, true>),
                           dim3(H_ / 256, YMAX1, 1), dim3(512), 0, stream,
                           xb, wT, b1, hbuf, counts, idx, tab1, ranges1, 0);
        // GEMM2: out = h @ w2 + b2, 128x128 BK=32, 256 thr, 6 blocks/CU TLP
        hipLaunchKernelGGL(transpose_cvt_kernel, dim3(C_ / 64, H_ / 64, E_),
                           dim3(256), 0, stream, w2, wT, H_, C_, 0);
        hipLaunchKernelGGL((gemm_kernel<128, 128, 32, 256, 2, 2, 6,
                                        YMAX2, H_, C_, float, false>),
                           dim3(C_ / 128, YMAX2, 1), dim3(256), 0, stream,
                           hbuf, wT, b2, out, counts, idx, tab2, ranges2, 0);
    } else {
        for (int c = 0; c < 2; c++) {
            hipLaunchKernelGGL(transpose_cvt_kernel, dim3(H_ / 64, C_ / 64, 4),
                               dim3(256), 0, stream, w1, wT, C_, H_, c * 4);
            hipLaunchKernelGGL((gemm_kernel<256, 256, 64, 512, 2, 4, 2,
                                            YMAX1, C_, H_, uint16_t, true>),
                               dim3(H_ / 256, YMAX1, 1), dim3(512), 0, stream,
                               xb, wT, b1, hbuf, counts, idx, tab1, ranges1 + 2 + 2 * c, c * 4);
        }
        for (int c = 0; c < 2; c++) {
            hipLaunchKernelGGL(transpose_cvt_kernel, dim3(C_ / 64, H_ / 64, 4),
                               dim3(256), 0, stream, w2, wT, H_, C_, c * 4);
            hipLaunchKernelGGL((gemm_kernel<128, 128, 32, 256, 2, 2, 6,
                                            YMAX2, H_, C_, float, false>),
                               dim3(C_ / 128, YMAX2, 1), dim3(256), 0, stream,
                               hbuf, wT, b2, out, counts, idx, tab2, ranges2 + 2 + 2 * c, c * 4);
        }
    }
}

// Round 5
// 568.236 us; speedup vs baseline: 2.2713x; 2.2713x over previous
//
#include <hip/hip_runtime.h>
#include <cstdint>
#include <cstddef>

#define NTOK 8192
#define C_ 1024
#define H_ 4096
#define E_ 8
#define YMAX 72  // max 128-row tiles over 8 experts: 8192/128 + 8 pad

typedef __attribute__((ext_vector_type(8))) short short8;
typedef __attribute__((ext_vector_type(4))) float f32x4;
typedef __attribute__((ext_vector_type(4))) unsigned int u32x4;

__device__ __forceinline__ uint16_t f2b(float f) {
    uint32_t x;
    __builtin_memcpy(&x, &f, 4);
    x = (x + 0x7fffu + ((x >> 16) & 1u)) >> 16;  // round-to-nearest-even
    return (uint16_t)x;
}

// tanh-form GELU, NaN-safe; |err vs erf-gelu| < ~3e-3 (threshold headroom 0.04)
__device__ __forceinline__ float gelu_f(float v) {
    float u = v * (0.7978845608028654f + 0.03567740814183f * v * v);
    float t = __expf(2.f * u);
    float th = 1.f - 2.f / (t + 1.f);
    return 0.5f * v * (1.f + th);
}

// ------- router: one wave per token, fp32 logits -> first-argmax ------------
// Also emits xb = bf16(x) (folds the old convert_x kernel into this pass).
__global__ __launch_bounds__(256) void router_kernel(
    const float* __restrict__ x, const float* __restrict__ wr,
    const float* __restrict__ br, int* __restrict__ top1,
    uint16_t* __restrict__ xb)
{
    int wid = threadIdx.x >> 6, lane = threadIdx.x & 63;
    int tok = blockIdx.x * 4 + wid;
    const float* xrow = x + (size_t)tok * C_;
    uint16_t* xbrow = xb + (size_t)tok * C_;
    float acc[E_];
#pragma unroll
    for (int e = 0; e < E_; e++) acc[e] = 0.f;
#pragma unroll 4
    for (int i = 0; i < C_ / 64; i++) {
        int c = i * 64 + lane;
        float xv = xrow[c];
        xbrow[c] = f2b(xv);
        const f32x4 w0 = *(const f32x4*)(wr + (size_t)c * E_);
        const f32x4 w1v = *(const f32x4*)(wr + (size_t)c * E_ + 4);
#pragma unroll
        for (int e = 0; e < 4; e++) acc[e] += xv * w0[e];
#pragma unroll
        for (int e = 0; e < 4; e++) acc[4 + e] += xv * w1v[e];
    }
#pragma unroll
    for (int off = 32; off > 0; off >>= 1) {
#pragma unroll
        for (int e = 0; e < E_; e++) acc[e] += __shfl_xor(acc[e], off, 64);
    }
    if (lane == 0) {
        float best = acc[0] + br[0];
        int bi = 0;
#pragma unroll
        for (int e = 1; e < E_; e++) {
            float v = acc[e] + br[e];
            if (v > best) { best = v; bi = e; }  // strict > == first-max (np argmax)
        }
        top1[tok] = bi;
    }
}

__global__ void zero_counts(int* counts) {
    if (threadIdx.x < E_) counts[threadIdx.x] = 0;
}

// two-level scatter: LDS histogram per block, 8 global atomics per block
// (order within an expert is irrelevant: outputs are written per-token).
__global__ __launch_bounds__(1024) void scatter_kernel(
    const int* __restrict__ top1, int* counts, int* __restrict__ idx)
{
    __shared__ int lc[E_], base[E_];
    int tid = threadIdx.x;
    if (tid < E_) lc[tid] = 0;
    __syncthreads();
    int t = blockIdx.x * 1024 + tid;
    int e = top1[t];
    int my = atomicAdd(&lc[e], 1);
    __syncthreads();
    if (tid < E_) base[tid] = atomicAdd(&counts[tid], lc[tid]);
    __syncthreads();
    idx[e * NTOK + base[e] + my] = t;
}

// ---- plan: compact (expert, mb) tile table for 128-row tiles ---------------
// ranges layout: [0..1]=all experts, [2..3]=experts 0..3, [4..5]=experts 4..7
__global__ void plan_kernel(const int* __restrict__ counts,
                            int* __restrict__ tab, int* __restrict__ ranges)
{
    if (threadIdx.x == 0) {
        int n = 0, n0 = 0;
        for (int e = 0; e < E_; e++) {
            int nt = (counts[e] + 127) >> 7;
            for (int mb = 0; mb < nt; mb++) tab[n++] = (e << 16) | mb;
            if (e == 3) n0 = n;
        }
        ranges[0] = 0;  ranges[1] = n;
        ranges[2] = 0;  ranges[3] = n0;
        ranges[4] = n0; ranges[5] = n;
    }
}

// ------- transpose+convert: w fp32 [E][K][N] -> wt bf16 [ez][N][K] ----------
__global__ __launch_bounds__(256) void transpose_cvt_kernel(
    const float* __restrict__ w, uint16_t* __restrict__ wt,
    int K, int N, int ebase)
{
    __shared__ uint16_t tile[64][66];
    int ez = blockIdx.z, e = ebase + ez;
    int n0 = blockIdx.x * 64, k0 = blockIdx.y * 64;
    int t = threadIdx.x;
#pragma unroll
    for (int i = 0; i < 4; i++) {
        int chunk = i * 256 + t;
        int r = chunk >> 4, c4 = chunk & 15;
        f32x4 v = *(const f32x4*)(w + (size_t)(e * K + k0 + r) * N + n0 + c4 * 4);
        uint32_t u0 = (uint32_t)f2b(v.x) | ((uint32_t)f2b(v.y) << 16);
        uint32_t u1 = (uint32_t)f2b(v.z) | ((uint32_t)f2b(v.w) << 16);
        *(uint32_t*)&tile[r][c4 * 4 + 0] = u0;
        *(uint32_t*)&tile[r][c4 * 4 + 2] = u1;
    }
    __syncthreads();
#pragma unroll
    for (int i = 0; i < 2; i++) {
        int chunk = i * 256 + t;
        int rn = chunk >> 3, ck = chunk & 7;
        uint32_t p[4];
#pragma unroll
        for (int j = 0; j < 4; j++) {
            uint32_t lo = tile[ck * 8 + 2 * j][rn];
            uint32_t hi = tile[ck * 8 + 2 * j + 1][rn];
            p[j] = lo | (hi << 16);
        }
        u32x4 v; v.x = p[0]; v.y = p[1]; v.z = p[2]; v.w = p[3];
        *(u32x4*)(wt + ((size_t)ez * N + n0 + rn) * K + k0 + ck * 8) = v;
    }
}

// ---------------- grouped GEMM: reg-staged, dbuf LDS, 1 barrier/step --------
// A bf16 [NTOK][K] gathered by token id; Bt bf16 [ez][N][K] k-contig.
// 128x128 tile, 256 thr = 4 waves (2x2), BK=32, per-wave 64x64 output.
// R3-proven reg staging (global_load_dwordx4 -> VGPR -> ds_write_b128),
// now double-buffered: iter kt = { issue loads(kt+1); compute(buf p);
// ds_write(buf 1-p); barrier } -- ONE barrier per K-step (was two); the
// vmcnt wait for the prefetch sits after compute's 16 MFMAs + 12 waves/CU
// of TLP. VGPR 64 + AGPR 64 = 128 -> MINW=3 is safe (R4 lesson: MINW=6
// capped the UNIFIED file at 85 and spilled acc to scratch: 843 us).
// LDS rows 32 elems = 4 chunks of 8; chunk j of row r holds global chunk
// j^((r>>1)&3) -> fragment ds_read_b128 conflict-free (measured 0).
// T1 (nb-major): each XCD owns GX/8 full B-panel columns -> w-panel (1 MB)
// is L2-resident across all token-tiles on that XCD.
template <int YB, int K, int N, typename OutT, bool GELU>
__global__ __launch_bounds__(256, 3) void gemm_kernel(
    const uint16_t* __restrict__ A, const uint16_t* __restrict__ Bt,
    const float* __restrict__ bias, OutT* __restrict__ Out,
    const int* __restrict__ counts, const int* __restrict__ idx,
    const int* __restrict__ tab, const int* __restrict__ range, int ebase)
{
    constexpr int BM = 128, BN = 128, NW = 256;
    constexpr int MR = 4;                   // m-frags per wave
    constexpr int NITER = K / 32;           // 32 or 128, even
    constexpr int GX = N / BN;
    constexpr int NWG = GX * YB;
    static_assert(NWG % 8 == 0, "grid must be divisible by 8 XCDs");
    static_assert((NITER & 1) == 0, "NITER must be even");

    // T1: XCD-chunked bijective swizzle, nb-major decode: XCD x owns lid
    // range [x*NWG/8, (x+1)*NWG/8) = GX/8 whole nb columns.
    int o = blockIdx.x * YB + blockIdx.y;
    int lid = (o & 7) * (NWG / 8) + (o >> 3);
    int nb = lid / YB;
    int tile = range[0] + lid % YB;
    if (tile >= range[1]) return;
    int ent = tab[tile];
    int e = ent >> 16, mb = ent & 0xffff;
    int ez = e - ebase;
    int cnt = counts[e];

    __shared__ __align__(16) uint16_t As[2][BM][32];
    __shared__ __align__(16) uint16_t Bs[2][BN][32];

    int t = threadIdx.x;
    int lane = t & 63, w = t >> 6;
    int wm = w >> 1, wn = w & 1;

    const int* idxe = idx + e * NTOK;

    f32x4 acc[MR][4];
#pragma unroll
    for (int mt = 0; mt < MR; mt++)
#pragma unroll
        for (int nt = 0; nt < 4; nt++) acc[mt][nt] = (f32x4)(0.f);

    const uint16_t* Bte = Bt + ((size_t)ez * N + (size_t)nb * BN) * K;

    // staging addresses: LDS chunk j (of 4 per 32-elem row) <- global chunk
    // j^((r>>1)&3) of the current 32-k window. 2 A insts + 2 B insts/thread.
    const uint16_t* aptr[2];
    const uint16_t* bptr[2];
#pragma unroll
    for (int i = 0; i < 2; i++) {
        int cid = i * NW + t;
        int r = cid >> 2, j = cid & 3;
        int s = mb * BM + r;
        int tk = idxe[(s < cnt) ? s : 0];
        aptr[i] = A + (size_t)tk * K + (j ^ ((r >> 1) & 3)) * 8;
    }
#pragma unroll
    for (int i = 0; i < 2; i++) {
        int cid = i * NW + t;
        int r = cid >> 2, j = cid & 3;
        bptr[i] = Bte + (size_t)r * K + (j ^ ((r >> 1) & 3)) * 8;
    }

    u32x4 ra[2], rb[2];
    auto loadreg = [&](int kt) {
        int k0 = kt * 32;
#pragma unroll
        for (int i = 0; i < 2; i++) ra[i] = *(const u32x4*)(aptr[i] + k0);
#pragma unroll
        for (int i = 0; i < 2; i++) rb[i] = *(const u32x4*)(bptr[i] + k0);
    };
    auto ldswrite = [&](int sel) {
#pragma unroll
        for (int i = 0; i < 2; i++)
            *(u32x4*)(&As[sel][0][0] + (size_t)(i * NW + t) * 8) = ra[i];
#pragma unroll
        for (int i = 0; i < 2; i++)
            *(u32x4*)(&Bs[sel][0][0] + (size_t)(i * NW + t) * 8) = rb[i];
    };

    // fragment chunk: global chunk (lane>>4) stored at chunk^(((lane&15)>>1)&3)
    int cs = (((lane >> 4) ^ ((lane & 15) >> 1)) & 3) * 8;

    auto compute = [&](int sel) {
        short8 af[MR], bf[4];
#pragma unroll
        for (int mt = 0; mt < MR; mt++)
            af[mt] = *(const short8*)
                (&As[sel][0][0] + (wm * 64 + mt * 16 + (lane & 15)) * 32 + cs);
#pragma unroll
        for (int nt = 0; nt < 4; nt++)
            bf[nt] = *(const short8*)
                (&Bs[sel][0][0] + (wn * 64 + nt * 16 + (lane & 15)) * 32 + cs);
#pragma unroll
        for (int mt = 0; mt < MR; mt++)
#pragma unroll
            for (int nt = 0; nt < 4; nt++)
                acc[mt][nt] = __builtin_amdgcn_mfma_f32_16x16x32_bf16(
                    af[mt], bf[nt], acc[mt][nt], 0, 0, 0);
    };

    // prologue: stage K-step 0 into buf 0
    loadreg(0);
    ldswrite(0);
    __syncthreads();

    // steady state (x2 unrolled for literal buffer selectors):
    // { issue loads(kt+1); compute(buf p); ds_write(buf 1-p); barrier }
    for (int kt = 0; kt + 2 < NITER; kt += 2) {
        loadreg(kt + 1);
        __builtin_amdgcn_sched_barrier(0);
        compute(0);
        ldswrite(1);
        __syncthreads();
        loadreg(kt + 2);
        __builtin_amdgcn_sched_barrier(0);
        compute(1);
        ldswrite(0);
        __syncthreads();
    }
    // kt == NITER-2
    loadreg(NITER - 1);
    __builtin_amdgcn_sched_barrier(0);
    compute(0);
    ldswrite(1);
    __syncthreads();
    compute(1);

    // epilogue: C/D layout col=lane&15, row=(lane>>4)*4+reg  [m89-verified]
    const float* be = bias + (size_t)e * N;
#pragma unroll
    for (int mt = 0; mt < MR; mt++) {
        int rbase = wm * 64 + mt * 16 + (lane >> 4) * 4;
#pragma unroll
        for (int r = 0; r < 4; r++) {
            int row = rbase + r;
            int s = mb * BM + row;
            if (s < cnt) {
                int tk = idxe[s];
#pragma unroll
                for (int nt = 0; nt < 4; nt++) {
                    int gcol = nb * BN + wn * 64 + nt * 16 + (lane & 15);
                    float v = acc[mt][nt][r] + be[gcol];
                    if (GELU) v = gelu_f(v);
                    if constexpr (sizeof(OutT) == 2)
                        Out[(size_t)tk * N + gcol] = (OutT)f2b(v);
                    else
                        Out[(size_t)tk * N + gcol] = v;
                }
            }
        }
    }
}

extern "C" void kernel_launch(void* const* d_in, const int* in_sizes, int n_in,
                              void* d_out, int out_size, void* d_ws, size_t ws_size,
                              hipStream_t stream)
{
    const float* x  = (const float*)d_in[0];
    const float* wr = (const float*)d_in[1];
    const float* br = (const float*)d_in[2];
    const float* b1 = (const float*)d_in[4];
    const float* w1 = (const float*)d_in[3];
    const float* w2 = (const float*)d_in[5];
    const float* b2 = (const float*)d_in[6];
    float* out = (float*)d_out;

    char* ws = (char*)d_ws;
    int* counts    = (int*)ws;                          // 32 B
    int* top1      = (int*)(ws + 1024);                 // 32 KiB
    int* idx       = (int*)(ws + 64 * 1024);            // 256 KiB
    int* tab       = (int*)(ws + 392 * 1024);           // 72 ints (128-row tiles)
    int* ranges    = (int*)(ws + 396 * 1024);           // 6 ints
    uint16_t* xb   = (uint16_t*)(ws + ((size_t)1 << 20));   // 16 MiB
    uint16_t* hbuf = (uint16_t*)(ws + ((size_t)17 << 20));  // 64 MiB
    uint16_t* wT   = (uint16_t*)(ws + ((size_t)81 << 20));  // 64 MiB (big) / 32 MiB

    // big path needs 81 + 64 = 145 MiB of ws; fallback (113 MiB) is proven.
    bool big = ws_size >= ((size_t)145 << 20);

    hipLaunchKernelGGL(zero_counts, dim3(1), dim3(64), 0, stream, counts);
    hipLaunchKernelGGL(router_kernel, dim3(NTOK / 4), dim3(256), 0, stream,
                       x, wr, br, top1, xb);
    hipLaunchKernelGGL(scatter_kernel, dim3(NTOK / 1024), dim3(1024), 0, stream,
                       top1, counts, idx);
    hipLaunchKernelGGL(plan_kernel, dim3(1), dim3(64), 0, stream,
                       counts, tab, ranges);

    if (big) {
        // GEMM1: h = gelu(x @ w1 + b1), 128x128 tiles, dbuf reg-staged
        hipLaunchKernelGGL(transpose_cvt_kernel, dim3(H_ / 64, C_ / 64, E_),
                           dim3(256), 0, stream, w1, wT, C_, H_, 0);
        hipLaunchKernelGGL((gemm_kernel<YMAX, C_, H_, uint16_t, true>),
                           dim3(H_ / 128, YMAX, 1), dim3(256), 0, stream,
                           xb, wT, b1, hbuf, counts, idx, tab, ranges, 0);
        // GEMM2: out = h @ w2 + b2, 128x128 tiles, dbuf reg-staged
        hipLaunchKernelGGL(transpose_cvt_kernel, dim3(C_ / 64, H_ / 64, E_),
                           dim3(256), 0, stream, w2, wT, H_, C_, 0);
        hipLaunchKernelGGL((gemm_kernel<YMAX, H_, C_, float, false>),
                           dim3(C_ / 128, YMAX, 1), dim3(256), 0, stream,
                           hbuf, wT, b2, out, counts, idx, tab, ranges, 0);
    } else {
        for (int c = 0; c < 2; c++) {
            hipLaunchKernelGGL(transpose_cvt_kernel, dim3(H_ / 64, C_ / 64, 4),
                               dim3(256), 0, stream, w1, wT, C_, H_, c * 4);
            hipLaunchKernelGGL((gemm_kernel<YMAX, C_, H_, uint16_t, true>),
                               dim3(H_ / 128, YMAX, 1), dim3(256), 0, stream,
                               xb, wT, b1, hbuf, counts, idx, tab, ranges + 2 + 2 * c, c * 4);
        }
        for (int c = 0; c < 2; c++) {
            hipLaunchKernelGGL(transpose_cvt_kernel, dim3(C_ / 64, H_ / 64, 4),
                               dim3(256), 0, stream, w2, wT, H_, C_, c * 4);
            hipLaunchKernelGGL((gemm_kernel<YMAX, H_, C_, float, false>),
                               dim3(C_ / 128, YMAX, 1), dim3(256), 0, stream,
                               hbuf, wT, b2, out, counts, idx, tab, ranges + 2 + 2 * c, c * 4);
        }
    }
}